// Round 1
// baseline (643.872 us; speedup 1.0000x reference)
//
#include <hip/hip_runtime.h>

// LSTMDecoder: B=4096, LATENT=128, SEQ=512, HID=32, OUT=64. f32 in/out.
// Round 9: decouple y-stores from the recurrence (theory: per-step 16-segment
// scattered global_store retire + allocator vmcnt(0) reuse was ~2400 cyc/step
// behind the block barrier).
//
//  - recurrence structure unchanged from r8: 8 waves (2/SIMD), sigma-permuted
//    transposed state frag `a` (f16x8), 4 duplicated gate MFMA tiles/wave,
//    1 cell activation per lane (10 transcendentals), hx LDS exchange with a
//    single lgkm-only barrier per step, parity-alternating buffers.
//  - NEW: projection results go to LDS (ytile[8 steps][16 rows][68], 34 KB,
//    +4-word row pad) via ds_write_b128 instead of per-step global stores.
//  - NEW: every 8 steps all 8 waves flush ytile: 4 x {ds_read_b128 ->
//    global_store_dwordx4} per wave, each store covering a CONTIGUOUS 1 KB
//    range (y[row][t0+s][c] is contiguous over (s,c)). Store regs are flush
//    temporaries with 8-step reuse distance -> no vmcnt on the step path.
//  - 2 extra lgkm barriers per 8-step group (pre-flush visibility, post-flush
//    anti-clobber). LDS total ~38 KB.

#define B_SZ   4096
#define LATENT 128
#define SEQ    512
#define HID    32
#define OUT_N  64
#define ROWS   16
#define LSW    40   // h0 staging row stride in halves (80 B rows)
#define YP     68   // ytile row stride in floats (64 + 4 pad words)

typedef _Float16 f16x8 __attribute__((ext_vector_type(8)));
typedef _Float16 f16x4 __attribute__((ext_vector_type(4)));
typedef float    f32x4 __attribute__((ext_vector_type(4)));

__device__ __forceinline__ float fexp2(float x) { return __builtin_amdgcn_exp2f(x); }
__device__ __forceinline__ float frcp(float x)  { return __builtin_amdgcn_rcpf(x); }
__device__ __forceinline__ float sigm(float x) {
    return frcp(1.f + fexp2(-1.44269504088896341f * x));
}
__device__ __forceinline__ float tanh_f(float x) {
    return fmaf(-2.f, frcp(1.f + fexp2(2.88539008177792681f * x)), 1.f);
}
__device__ __forceinline__ void lds_barrier() {
    asm volatile("s_waitcnt lgkmcnt(0)\n\ts_barrier" ::: "memory");
}

__global__ __launch_bounds__(512)
void lstm_tr9(const float* __restrict__ z,
              const float* __restrict__ init_W,
              const float* __restrict__ init_b,
              const float* __restrict__ W_hh,
              const float* __restrict__ b_ih,
              const float* __restrict__ b_hh,
              const float* __restrict__ out_W,
              const float* __restrict__ out_b,
              float* __restrict__ y)
{
    __shared__ __align__(16) _Float16 hst[ROWS * LSW];
    __shared__ __align__(8) unsigned short hx[2][2][64][4];  // [par][jj][lane][r]
    __shared__ __align__(16) float ytile[8 * 16 * YP];       // 34 KB y staging

    const int tid  = threadIdx.x;
    const int w    = tid >> 6;          // wave 0..7
    const int lane = tid & 63;
    const int n_   = lane & 15;         // batch row within tile
    const int kb   = lane >> 4;         // k-group / D row-group
    const int jj   = w & 1;             // cell half
    const int r_   = w >> 1;            // D reg this wave activates (0..3)
    const int rbase = blockIdx.x * ROWS;

    // ---- resident W_hh A-frags for tiles {jj,2+jj,4+jj,6+jj} (sigma-permuted k) ----
    f16x8 wf[4];
    f32x4 bacc[4];
#pragma unroll
    for (int m = 0; m < 4; m++) {
        int g = 2 * m + jj;
        const float* row = W_hh + (size_t)(16 * g + n_) * HID;
        f16x8 v;
#pragma unroll
        for (int rr = 0; rr < 4; rr++) {
            v[rr]     = (_Float16)row[4 * kb + rr];
            v[4 + rr] = (_Float16)row[4 * kb + 16 + rr];
        }
        wf[m] = v;
        f32x4 b;
#pragma unroll
        for (int r = 0; r < 4; r++) {
            int G = 16 * g + 4 * kb + r;
            b[r] = b_ih[G] + b_hh[G];
        }
        bacc[m] = b;
    }
    // ---- proj A-frag (jj==0 waves own tile p=r_) ----
    f16x8 owf;
    f32x4 oacc;
    {
        int p = r_;
        const float* row = out_W + (size_t)(16 * p + n_) * HID;
        f16x8 v;
#pragma unroll
        for (int rr = 0; rr < 4; rr++) {
            v[rr]     = (_Float16)row[4 * kb + rr];
            v[4 + rr] = (_Float16)row[4 * kb + 16 + rr];
        }
        owf = v;
#pragma unroll
        for (int r = 0; r < 4; r++) oacc[r] = out_b[16 * p + 4 * kb + r];
    }

    // ---- h0 = z @ init_W^T + init_b (one cell per thread: 512 = 16x32) ----
    {
        int m = tid >> 5, j = tid & 31;
        const float4* zp = (const float4*)(z + (size_t)(rbase + m) * LATENT);
        const float4* wp = (const float4*)(init_W + (size_t)j * LATENT);
        float acc = init_b[j];
#pragma unroll
        for (int k = 0; k < LATENT / 4; k++) {
            float4 a4 = zp[k], b4 = wp[k];
            acc = fmaf(a4.x, b4.x, acc); acc = fmaf(a4.y, b4.y, acc);
            acc = fmaf(a4.z, b4.z, acc); acc = fmaf(a4.w, b4.w, acc);
        }
        hst[m * LSW + j] = (_Float16)acc;
    }
    __syncthreads();

    // initial fragment: slot 4jj'+rr <- h0[n_][4kb+16jj'+rr]
    f16x8 a;
    {
        f16x4 lo = *(const f16x4*)&hst[n_ * LSW + 4 * kb];
        f16x4 hi = *(const f16x4*)&hst[n_ * LSW + 4 * kb + 16];
#pragma unroll
        for (int r = 0; r < 4; r++) { a[r] = lo[r]; a[4 + r] = hi[r]; }
    }

    float c1 = 0.f;   // cell 4kb+16jj+r_, row n_

    for (int t0 = 0; t0 < SEQ; t0 += 8) {
#pragma unroll
        for (int u = 0; u < 8; u++) {
            const int par = u & 1;
            // ---- gates (4 tiles, duplicated across r-waves) ----
            f32x4 acc[4];
#pragma unroll
            for (int m = 0; m < 4; m++)
                acc[m] = __builtin_amdgcn_mfma_f32_16x16x32_f16(wf[m], a, bacc[m], 0, 0, 0);

            // ---- activation for this wave's single cell ----
            {
                float gi = sigm(acc[0][r_]);
                float gf = sigm(acc[1][r_]);
                float gg = tanh_f(acc[2][r_]);
                float go = sigm(acc[3][r_]);
                float cn = fmaf(gf, c1, gi * gg);
                c1 = cn;
                union { _Float16 h; unsigned short u16; } cv;
                cv.h = (_Float16)(go * tanh_f(cn));
                hx[par][jj][lane][r_] = cv.u16;
            }
            lds_barrier();

            // ---- rebuild fragment: two b64 reads, in-lane ----
            f16x4 lo = *(const f16x4*)&hx[par][0][lane][0];
            f16x4 hi = *(const f16x4*)&hx[par][1][lane][0];
#pragma unroll
            for (int r = 0; r < 4; r++) { a[r] = lo[r]; a[4 + r] = hi[r]; }

            // ---- projection (jj==0 waves) -> LDS staging, NOT global ----
            if (jj == 0) {
                f32x4 py = __builtin_amdgcn_mfma_f32_16x16x32_f16(owf, a, oacc, 0, 0, 0);
                *(f32x4*)&ytile[(u * 16 + n_) * YP + 16 * r_ + 4 * kb] = py;
            }
        }

        // all ytile writes (issued before each wave's own lgkm wait) visible
        lds_barrier();

        // ---- flush 8 steps of y: wave w owns rows {2w, 2w+1} ----
        // each iter: 64 lanes read 1 KB from LDS, store 1 KB CONTIGUOUS global
        {
            const int s = (lane >> 4);        // s-subgroup 0..3 within iter
            const int c = (lane & 15) * 4;    // col within row
#pragma unroll
            for (int i = 0; i < 4; i++) {
                const int row = 2 * w + (i >> 1);
                const int ss  = (i & 1) * 4 + s;
                f32x4 v = *(const f32x4*)&ytile[(ss * 16 + row) * YP + c];
                *(f32x4*)(y + (size_t)(rbase + row) * SEQ * OUT_N
                            + (size_t)(t0 + ss) * OUT_N + c) = v;
            }
        }

        // flush reads complete before next group's ytile writes
        lds_barrier();
    }
}

extern "C" void kernel_launch(void* const* d_in, const int* in_sizes, int n_in,
                              void* d_out, int out_size, void* d_ws, size_t ws_size,
                              hipStream_t stream) {
    const float* z      = (const float*)d_in[0];
    const float* init_W = (const float*)d_in[1];
    const float* init_b = (const float*)d_in[2];
    // d_in[3] = W_ih: unused (x input is all zeros; only biases survive)
    const float* W_hh   = (const float*)d_in[4];
    const float* b_ih   = (const float*)d_in[5];
    const float* b_hh   = (const float*)d_in[6];
    const float* out_W  = (const float*)d_in[7];
    const float* out_b  = (const float*)d_in[8];
    float* yout = (float*)d_out;

    lstm_tr9<<<B_SZ / ROWS, 512, 0, stream>>>(z, init_W, init_b, W_hh, b_ih, b_hh,
                                              out_W, out_b, yout);
}

// Round 2
// 604.983 us; speedup vs baseline: 1.0643x; 1.0643x over previous
//
#include <hip/hip_runtime.h>

// LSTMDecoder: B=4096, LATENT=128, SEQ=512, HID=32, OUT=64. f32 in/out.
// Round 10: shorten the serial per-step chain (store path proven irrelevant in r9).
//
//  - FUSED GATE MFMA: per-wave row-permuted A-matrix Atil, tile-row d :=
//    W_hh gate-row 32*(d&3) + 16*jj + 4*(d>>2) + r_. One mfma_16x16x32_f16
//    yields regs 0..3 = (i,f,g,o) of THIS wave's cell (4kb+16jj+r_) at lane
//    (n_,kb). Replaces 4 duplicated tile-MFMAs; frees ~28 VGPRs.
//  - SCALE FOLD: -log2e (i,f,o) / +2*log2e (g) folded into f16 weights and
//    bias, deleting one v_mul per gate on the transcendental chain.
//    gi/gf/go = rcp(1+exp2(acc)); gg = fmaf(-2, rcp(1+exp2(acc)), 1).
//  - ONE-SHOT EXCHANGE: hx2[par][lane][slot 4jj+r_] u16; rebuild is a single
//    ds_read_b128 landing directly in B-frag slot order (no repack movs).
//    Parity double-buffer => still exactly 1 lgkm barrier per step.
//  - BALANCED PROJ: group jj==(u&1) does the projection MFMA + store each
//    step, so neither jj-group is the permanent barrier straggler.
//  - Direct per-step global stores (r9's LDS y-staging was neutral: reverted).

#define B_SZ   4096
#define LATENT 128
#define SEQ    512
#define HID    32
#define OUT_N  64
#define ROWS   16
#define LSW    40   // h0 staging row stride in halves (80 B rows)

typedef _Float16 f16x8 __attribute__((ext_vector_type(8)));
typedef _Float16 f16x4 __attribute__((ext_vector_type(4)));
typedef float    f32x4 __attribute__((ext_vector_type(4)));

__device__ __forceinline__ float fexp2(float x) { return __builtin_amdgcn_exp2f(x); }
__device__ __forceinline__ float frcp(float x)  { return __builtin_amdgcn_rcpf(x); }
__device__ __forceinline__ float tanh_f(float x) {
    return fmaf(-2.f, frcp(1.f + fexp2(2.88539008177792681f * x)), 1.f);
}
__device__ __forceinline__ void lds_barrier() {
    asm volatile("s_waitcnt lgkmcnt(0)\n\ts_barrier" ::: "memory");
}

__global__ __launch_bounds__(512)
void lstm_tr10(const float* __restrict__ z,
               const float* __restrict__ init_W,
               const float* __restrict__ init_b,
               const float* __restrict__ W_hh,
               const float* __restrict__ b_ih,
               const float* __restrict__ b_hh,
               const float* __restrict__ out_W,
               const float* __restrict__ out_b,
               float* __restrict__ y)
{
    __shared__ __align__(16) _Float16 hst[ROWS * LSW];
    __shared__ __align__(16) unsigned short hx2[2][64][8];  // [par][lane][slot]

    const int tid  = threadIdx.x;
    const int w    = tid >> 6;          // wave 0..7
    const int lane = tid & 63;
    const int n_   = lane & 15;         // batch row within tile
    const int kb   = lane >> 4;         // k-group / D row-group
    const int jj   = w & 1;             // cell half
    const int r_   = w >> 1;            // cell sub-index this wave activates (0..3)
    const int rbase = blockIdx.x * ROWS;

    const float NL2E = -1.44269504088896341f;   // -log2(e), for sigmoid gates
    const float P2L2E = 2.88539008177792681f;   // +2*log2(e), for g (tanh) gate

    // ---- fused gate A-frag: Atil row d = W_hh row 32*(d&3)+16jj+4*(d>>2)+r_ ----
    f16x8 wf1;
    f32x4 bacc1;
    {
        const int arow = 32 * (n_ & 3) + 16 * jj + 4 * (n_ >> 2) + r_;
        const float asc = ((n_ & 3) == 2) ? P2L2E : NL2E;
        const float* wrow = W_hh + (size_t)arow * HID;
#pragma unroll
        for (int rr = 0; rr < 4; rr++) {
            wf1[rr]     = (_Float16)(asc * wrow[4 * kb + rr]);
            wf1[4 + rr] = (_Float16)(asc * wrow[16 + 4 * kb + rr]);
        }
#pragma unroll
        for (int r = 0; r < 4; r++) {
            const int G = 32 * r + 16 * jj + 4 * kb + r_;
            const float bsc = (r == 2) ? P2L2E : NL2E;
            bacc1[r] = bsc * (b_ih[G] + b_hh[G]);
        }
    }

    // ---- proj A-frag (each wave owns tile p=r_; both jj groups keep a copy) ----
    f16x8 owf;
    f32x4 oacc;
    {
        const int p = r_;
        const float* row = out_W + (size_t)(16 * p + n_) * HID;
#pragma unroll
        for (int rr = 0; rr < 4; rr++) {
            owf[rr]     = (_Float16)row[4 * kb + rr];
            owf[4 + rr] = (_Float16)row[4 * kb + 16 + rr];
        }
#pragma unroll
        for (int r = 0; r < 4; r++) oacc[r] = out_b[16 * p + 4 * kb + r];
    }

    // ---- h0 = z @ init_W^T + init_b (one cell per thread: 512 = 16x32) ----
    {
        int m = tid >> 5, j = tid & 31;
        const float4* zp = (const float4*)(z + (size_t)(rbase + m) * LATENT);
        const float4* wp = (const float4*)(init_W + (size_t)j * LATENT);
        float acc = init_b[j];
#pragma unroll
        for (int k = 0; k < LATENT / 4; k++) {
            float4 a4 = zp[k], b4 = wp[k];
            acc = fmaf(a4.x, b4.x, acc); acc = fmaf(a4.y, b4.y, acc);
            acc = fmaf(a4.z, b4.z, acc); acc = fmaf(a4.w, b4.w, acc);
        }
        hst[m * LSW + j] = (_Float16)acc;
    }
    __syncthreads();

    // initial fragment: slot 4jj'+rr <- h0[n_][4kb+16jj'+rr]
    f16x8 a;
    {
        f16x4 lo = *(const f16x4*)&hst[n_ * LSW + 4 * kb];
        f16x4 hi = *(const f16x4*)&hst[n_ * LSW + 4 * kb + 16];
#pragma unroll
        for (int r = 0; r < 4; r++) { a[r] = lo[r]; a[4 + r] = hi[r]; }
    }

    float c1 = 0.f;   // cell 4kb+16jj+r_, row n_

    float* yb = y + (size_t)(rbase + n_) * SEQ * OUT_N + 16 * r_ + 4 * kb;

    for (int t = 0; t < SEQ; t += 4) {
#pragma unroll
        for (int u = 0; u < 4; u++) {
            const int par = u & 1;
            // ---- one fused gate MFMA: regs 0..3 = scaled (i,f,g,o) pre-acts ----
            f32x4 acc = __builtin_amdgcn_mfma_f32_16x16x32_f16(wf1, a, bacc1, 0, 0, 0);

            // ---- activation (scale pre-folded into weights/bias) ----
            {
                float gi = frcp(1.f + fexp2(acc[0]));
                float gf = frcp(1.f + fexp2(acc[1]));
                float gg = fmaf(-2.f, frcp(1.f + fexp2(acc[2])), 1.f);
                float go = frcp(1.f + fexp2(acc[3]));
                float cn = fmaf(gf, c1, gi * gg);
                c1 = cn;
                union { _Float16 h; unsigned short u16; } cv;
                cv.h = (_Float16)(go * tanh_f(cn));
                hx2[par][lane][4 * jj + r_] = cv.u16;
            }
            lds_barrier();

            // ---- rebuild fragment: ONE ds_read_b128, already in slot order ----
            a = *(const f16x8*)&hx2[par][lane][0];

            // ---- projection: group jj==par this step (load-balanced) ----
            if (jj == par) {
                f32x4 py = __builtin_amdgcn_mfma_f32_16x16x32_f16(owf, a, oacc, 0, 0, 0);
                *(f32x4*)(yb + (size_t)(t + u) * OUT_N) = py;
            }
        }
    }
}

extern "C" void kernel_launch(void* const* d_in, const int* in_sizes, int n_in,
                              void* d_out, int out_size, void* d_ws, size_t ws_size,
                              hipStream_t stream) {
    const float* z      = (const float*)d_in[0];
    const float* init_W = (const float*)d_in[1];
    const float* init_b = (const float*)d_in[2];
    // d_in[3] = W_ih: unused (x input is all zeros; only biases survive)
    const float* W_hh   = (const float*)d_in[4];
    const float* b_ih   = (const float*)d_in[5];
    const float* b_hh   = (const float*)d_in[6];
    const float* out_W  = (const float*)d_in[7];
    const float* out_b  = (const float*)d_in[8];
    float* yout = (float*)d_out;

    lstm_tr10<<<B_SZ / ROWS, 512, 0, stream>>>(z, init_W, init_b, W_hh, b_ih, b_hh,
                                               out_W, out_b, yout);
}

// Round 3
// 583.463 us; speedup vs baseline: 1.1035x; 1.0369x over previous
//
#include <hip/hip_runtime.h>

// LSTMDecoder: B=4096, LATENT=128, SEQ=512, HID=32, OUT=64. f32 in/out.
// Round 11: kill the exchange-write bank conflict + reorder chain.
//
//  - r10 baseline: fused single gate MFMA (permuted Atil, scale-folded),
//    one-shot LDS exchange, 1 barrier/step, 8 waves, 1 cell/lane.
//  - FIX: hx2 rows padded 16B->20B ([2][64][10] u16). Old layout's
//    ds_write_b16 hit bank (4*lane)%32 = 8-way conflict x 8 waves right
//    before the barrier wait. Padded: banks (5*lane+c)%32 = 2-way (free).
//    Rebuild = 4x ds_read_b32 (4-aligned, conflict-free, slot-ordered).
//  - PROJ HOIST: at step s, project a=h_s -> y[s-1] BEFORE the gate MFMA
//    (proj is one step deferred; tail y[511] after the loop). Gate MFMA now
//    issues immediately when the exchange read lands; proj+store run under
//    the act chain on the matrix/memory pipes.
//  - ACT: c-state kept pre-scaled by 2*log2e; h = fmaf(-2*go, rcp, go);
//    P2L2E*gg via constant-folded fma. 2 fewer serial muls.

#define B_SZ   4096
#define LATENT 128
#define SEQ    512
#define HID    32
#define OUT_N  64
#define ROWS   16
#define LSW    40   // h0 staging row stride in halves (80 B rows)
#define HXW    10   // hx2 row stride in halves (20 B rows)

typedef _Float16 f16x8 __attribute__((ext_vector_type(8)));
typedef _Float16 f16x4 __attribute__((ext_vector_type(4)));
typedef float    f32x4 __attribute__((ext_vector_type(4)));

__device__ __forceinline__ float fexp2(float x) { return __builtin_amdgcn_exp2f(x); }
__device__ __forceinline__ float frcp(float x)  { return __builtin_amdgcn_rcpf(x); }
__device__ __forceinline__ void lds_barrier() {
    asm volatile("s_waitcnt lgkmcnt(0)\n\ts_barrier" ::: "memory");
}

__global__ __launch_bounds__(512)
void lstm_tr11(const float* __restrict__ z,
               const float* __restrict__ init_W,
               const float* __restrict__ init_b,
               const float* __restrict__ W_hh,
               const float* __restrict__ b_ih,
               const float* __restrict__ b_hh,
               const float* __restrict__ out_W,
               const float* __restrict__ out_b,
               float* __restrict__ y)
{
    __shared__ __align__(16) _Float16 hst[ROWS * LSW];
    __shared__ __align__(16) unsigned short hx2[2][64][HXW];  // 20 B rows

    const int tid  = threadIdx.x;
    const int w    = tid >> 6;          // wave 0..7
    const int lane = tid & 63;
    const int n_   = lane & 15;         // batch row within tile
    const int kb   = lane >> 4;         // k-group / D row-group
    const int jj   = w & 1;             // cell half
    const int r_   = w >> 1;            // cell sub-index this wave activates (0..3)
    const int rbase = blockIdx.x * ROWS;

    const float NL2E  = -1.44269504088896341f;   // -log2(e)
    const float P2L2E =  2.88539008177792681f;   // +2*log2(e)

    // ---- fused gate A-frag: Atil row d = W_hh row 32*(d&3)+16jj+4*(d>>2)+r_ ----
    f16x8 wf1;
    f32x4 bacc1;
    {
        const int arow = 32 * (n_ & 3) + 16 * jj + 4 * (n_ >> 2) + r_;
        const float asc = ((n_ & 3) == 2) ? P2L2E : NL2E;
        const float* wrow = W_hh + (size_t)arow * HID;
#pragma unroll
        for (int rr = 0; rr < 4; rr++) {
            wf1[rr]     = (_Float16)(asc * wrow[4 * kb + rr]);
            wf1[4 + rr] = (_Float16)(asc * wrow[16 + 4 * kb + rr]);
        }
#pragma unroll
        for (int r = 0; r < 4; r++) {
            const int G = 32 * r + 16 * jj + 4 * kb + r_;
            const float bsc = (r == 2) ? P2L2E : NL2E;
            bacc1[r] = bsc * (b_ih[G] + b_hh[G]);
        }
    }

    // ---- proj A-frag (each wave owns tile p=r_; both jj groups keep a copy) ----
    f16x8 owf;
    f32x4 oacc;
    {
        const int p = r_;
        const float* row = out_W + (size_t)(16 * p + n_) * HID;
#pragma unroll
        for (int rr = 0; rr < 4; rr++) {
            owf[rr]     = (_Float16)row[4 * kb + rr];
            owf[4 + rr] = (_Float16)row[4 * kb + 16 + rr];
        }
#pragma unroll
        for (int r = 0; r < 4; r++) oacc[r] = out_b[16 * p + 4 * kb + r];
    }

    // ---- h0 = z @ init_W^T + init_b (one cell per thread: 512 = 16x32) ----
    {
        int m = tid >> 5, j = tid & 31;
        const float4* zp = (const float4*)(z + (size_t)(rbase + m) * LATENT);
        const float4* wp = (const float4*)(init_W + (size_t)j * LATENT);
        float acc = init_b[j];
#pragma unroll
        for (int k = 0; k < LATENT / 4; k++) {
            float4 a4 = zp[k], b4 = wp[k];
            acc = fmaf(a4.x, b4.x, acc); acc = fmaf(a4.y, b4.y, acc);
            acc = fmaf(a4.z, b4.z, acc); acc = fmaf(a4.w, b4.w, acc);
        }
        hst[m * LSW + j] = (_Float16)acc;
    }
    __syncthreads();

    // initial fragment: slot 4jj'+rr <- h0[n_][4kb+16jj'+rr]
    f16x8 a;
    {
        f16x4 lo = *(const f16x4*)&hst[n_ * LSW + 4 * kb];
        f16x4 hi = *(const f16x4*)&hst[n_ * LSW + 4 * kb + 16];
#pragma unroll
        for (int r = 0; r < 4; r++) { a[r] = lo[r]; a[4 + r] = hi[r]; }
    }

    float cs = 0.f;   // 2*log2e - scaled cell state of cell 4kb+16jj+r_, row n_

    float* yb = y + (size_t)(rbase + n_) * SEQ * OUT_N + 16 * r_ + 4 * kb;

    for (int t = 0; t < SEQ; t += 4) {
#pragma unroll
        for (int u = 0; u < 4; u++) {
            const int par = u & 1;
            // ---- gate MFMA first: issues the moment the exchange read lands ----
            f32x4 acc = __builtin_amdgcn_mfma_f32_16x16x32_f16(wf1, a, bacc1, 0, 0, 0);

            // ---- deferred projection: a = h_s, store y[s-1] (group jj==par) ----
            if (jj == par) {
                f32x4 py = __builtin_amdgcn_mfma_f32_16x16x32_f16(owf, a, oacc, 0, 0, 0);
                if (t + u) *(f32x4*)(yb + (size_t)(t + u - 1) * OUT_N) = py;
            }

            // ---- activation (scales pre-folded; cs = 2log2e * c) ----
            {
                float gi = frcp(1.f + fexp2(acc[0]));
                float gf = frcp(1.f + fexp2(acc[1]));
                float rg = frcp(1.f + fexp2(acc[2]));
                float go = frcp(1.f + fexp2(acc[3]));
                float g2 = fmaf(-2.f * P2L2E, rg, P2L2E);  // 2log2e * tanh(pre_g)
                float csn = fmaf(gf, cs, gi * g2);
                cs = csn;
                float rt = frcp(1.f + fexp2(csn));
                float hh = fmaf(-2.f * go, rt, go);        // go * tanh(c)
                union { _Float16 h; unsigned short u16; } cv;
                cv.h = (_Float16)hh;
                hx2[par][lane][4 * jj + r_] = cv.u16;
            }
            lds_barrier();

            // ---- rebuild fragment: 4x ds_read_b32, conflict-free, slot order ----
            {
                union { unsigned int u[4]; f16x8 v; } ua;
                const unsigned int* rp = (const unsigned int*)&hx2[par][lane][0];
                ua.u[0] = rp[0]; ua.u[1] = rp[1]; ua.u[2] = rp[2]; ua.u[3] = rp[3];
                a = ua.v;
            }
        }
    }

    // ---- tail: y[511] = proj(h_512) (jj==0 group; par of step 512 is 0) ----
    if (jj == 0) {
        f32x4 py = __builtin_amdgcn_mfma_f32_16x16x32_f16(owf, a, oacc, 0, 0, 0);
        *(f32x4*)(yb + (size_t)(SEQ - 1) * OUT_N) = py;
    }
}

extern "C" void kernel_launch(void* const* d_in, const int* in_sizes, int n_in,
                              void* d_out, int out_size, void* d_ws, size_t ws_size,
                              hipStream_t stream) {
    const float* z      = (const float*)d_in[0];
    const float* init_W = (const float*)d_in[1];
    const float* init_b = (const float*)d_in[2];
    // d_in[3] = W_ih: unused (x input is all zeros; only biases survive)
    const float* W_hh   = (const float*)d_in[4];
    const float* b_ih   = (const float*)d_in[5];
    const float* b_hh   = (const float*)d_in[6];
    const float* out_W  = (const float*)d_in[7];
    const float* out_b  = (const float*)d_in[8];
    float* yout = (float*)d_out;

    lstm_tr11<<<B_SZ / ROWS, 512, 0, stream>>>(z, init_W, init_b, W_hh, b_ih, b_hh,
                                               out_W, out_b, yout);
}